// Round 2
// baseline (860.156 us; speedup 1.0000x reference)
//
#include <hip/hip_runtime.h>
#include <hip/hip_fp16.h>

// GCN 3-layer. Two-pass build (R12-proven): scatter1 -> 123 superbuckets of
// 4096 nodes (clean full-line write-back), buildfine -> block per 1024-node
// fine bucket, in-LDS counting sort -> csr + rowptr/dinv/z1 fused.
// Layers: thread-per-node unrolled gathers (zero atomics).
// R13: z2 4xfp16 (8B/node, 4MB table). R14: z1/z3 half2 (4B/node, 2MB tables)
// -> gcn1/gcn3 fell out of top-5; gcn2 now the wall (147us, FETCH 324MB vs
// ~74MB ideal: its 4MB table == per-XCD L2, csr stream evicts it).
// R15 change: src-partitioned gcn2 -> two passes, each gathering only from
// one 2MB half of z2h (src<N/2 in pass A, src>=N/2 in pass B), fp32 partial
// sums handed A->B, epilogue fused in B. Hot table per pass = 2MB (proven
// residency size from gcn1/gcn3). Masked lanes redirect to one shared hot
// line (no L2 request). Self-term split by node half (no foreign-half
// streaming). Cost: csr streamed twice (+64MB) + 8MB partials.
// Math per layer (input u): z = u*dinv; s_i = sum_{e:dst=i} z[src_e];
//   out_i = (dinv_i*(s_i + z_i)) @ W + b   (self-loop folds into s+z).
// pk1 = (dst&4095) | (src<<12)  (31 bits, N < 2^19).

#define TPB 256
#define T_TILE 32768
#define SBB 12           // superbucket = 4096 nodes
#define NSB_MAX 128
#define FINE_BITS 10     // fine bucket = 1024 nodes, 4 per superbucket
#define EB_CAP 34048     // mean fine bucket 32.7K edges, +7 sigma

// ---------------- pass 0: per-tile superbucket histogram ----------------

__global__ void __launch_bounds__(512)
count1(const int* __restrict__ dst, int* __restrict__ cnt1, int ntB, int E, int SB) {
    __shared__ int hist[NSB_MAX];
    int blk = blockIdx.x, tid = threadIdx.x;
    if (tid < SB) hist[tid] = 0;
    __syncthreads();
    int base = blk * T_TILE;
    #pragma unroll 8
    for (int it = 0; it < T_TILE / 512; ++it) {
        int e = base + it * 512 + tid;
        if (e < E) atomicAdd(&hist[((unsigned)dst[e]) >> SBB], 1);
    }
    __syncthreads();
    if (tid < SB) cnt1[(size_t)tid * ntB + blk] = hist[tid];
}

// ---- 3-kernel exclusive scan over data[len] (in-place), 1024 elems/block ----
__global__ void scan_k1(const int* __restrict__ data, int* __restrict__ bsum, int len) {
    __shared__ int lds[TPB];
    int b = blockIdx.x, t = threadIdx.x;
    int base = b * 1024 + t * 4;
    int s = 0;
    #pragma unroll
    for (int j = 0; j < 4; ++j) { int i = base + j; if (i < len) s += data[i]; }
    lds[t] = s; __syncthreads();
    for (int off = 128; off > 0; off >>= 1) {
        if (t < off) lds[t] += lds[t + off];
        __syncthreads();
    }
    if (t == 0) bsum[b] = lds[0];
}

__global__ void scan_k2(int* __restrict__ bsum, int NB) {
    __shared__ int lds[1024];
    int t = threadIdx.x;
    int v = (t < NB) ? bsum[t] : 0;
    lds[t] = v; __syncthreads();
    for (int off = 1; off < 1024; off <<= 1) {
        int add = (t >= off) ? lds[t - off] : 0;
        __syncthreads();
        lds[t] += add;
        __syncthreads();
    }
    if (t < NB) bsum[t] = lds[t] - v;  // exclusive
}

__global__ void scan_k3(int* __restrict__ data, const int* __restrict__ bsum, int len) {
    __shared__ int lds[TPB];
    int b = blockIdx.x, t = threadIdx.x;
    int base = b * 1024 + t * 4;
    int v[4]; int s = 0;
    #pragma unroll
    for (int j = 0; j < 4; ++j) { int i = base + j; v[j] = (i < len) ? data[i] : 0; s += v[j]; }
    int orig = s;
    lds[t] = s; __syncthreads();
    for (int off = 1; off < 256; off <<= 1) {
        int add = (t >= off) ? lds[t - off] : 0;
        __syncthreads();
        lds[t] += add;
        __syncthreads();
    }
    int run = bsum[b] + lds[t] - orig;
    #pragma unroll
    for (int j = 0; j < 4; ++j) {
        int i = base + j;
        if (i < len) { data[i] = run; run += v[j]; }
    }
}

__global__ void bases_fix(const int* __restrict__ cnt1, int ntB, int SB,
                          int* __restrict__ bases1, int* __restrict__ rowptr,
                          int N, int E) {
    int t = threadIdx.x;
    if (t < SB) bases1[t] = cnt1[(size_t)t * ntB];
    if (t == 0) { bases1[SB] = E; rowptr[N] = E; }
}

// ---- pass 1: scatter into superbucket regions (clean write-back) ----
__global__ void __launch_bounds__(512)
scatter1(const int* __restrict__ dst, const int* __restrict__ src,
         const int* __restrict__ cnt1, unsigned* __restrict__ pk1,
         int ntB, int E, int SB) {
    __shared__ int basec[NSB_MAX];
    int blk = blockIdx.x, tid = threadIdx.x;
    if (tid < SB) basec[tid] = cnt1[(size_t)tid * ntB + blk];
    __syncthreads();
    int base = blk * T_TILE;
    #pragma unroll 8
    for (int it = 0; it < T_TILE / 512; ++it) {
        int e = base + it * 512 + tid;
        if (e < E) {
            unsigned d = (unsigned)dst[e];
            unsigned s = (unsigned)src[e];
            int pos = atomicAdd(&basec[d >> SBB], 1);
            pk1[pos] = (d & 4095u) | (s << SBB);
        }
    }
}

// ---- pass 2: fused fine+node sort -> csr + rowptr + dinv + z1 (half2) ----
__global__ void __launch_bounds__(1024)
buildfine(const int* __restrict__ bases1, const unsigned* __restrict__ pk1,
          const float* __restrict__ x, int* __restrict__ rowptr,
          float* __restrict__ dinv, unsigned* __restrict__ z1h,
          unsigned* __restrict__ csr, int N) {
    __shared__ int cnt[1024];
    __shared__ int tmp[1024];
    __shared__ int cur[1024];
    __shared__ unsigned eb[EB_CAP];
    __shared__ int redbase;
    int bid = blockIdx.x, tid = threadIdx.x;
    int sb = bid >> 2, j = bid & 3;
    int node0 = (sb << SBB) + (j << FINE_BITS);
    int ebeg = bases1[sb], eend = bases1[sb + 1];
    int n = eend - ebeg;
    cnt[tid] = 0;
    if (tid == 0) redbase = 0;
    __syncthreads();
    int lane = tid & 63;
    int myprev = 0;  // wave count of region edges with fine-id < j
    int k0 = 0;
    for (; k0 + 8192 <= n; k0 += 8192) {
        unsigned p[8];
        #pragma unroll
        for (int u = 0; u < 8; ++u) p[u] = pk1[ebeg + k0 + tid + u * 1024];
        #pragma unroll
        for (int u = 0; u < 8; ++u) {
            int f = (int)((p[u] >> FINE_BITS) & 3u);
            myprev += (int)__popcll(__ballot(f < j));
            if (f == j) atomicAdd(&cnt[p[u] & 1023u], 1);
        }
    }
    for (int kk = k0; kk < n; kk += 1024) {
        int k = kk + tid;
        bool valid = (k < n);
        unsigned p = valid ? pk1[ebeg + k] : 0u;
        int f = valid ? (int)((p >> FINE_BITS) & 3u) : 4;
        myprev += (int)__popcll(__ballot(valid && f < j));
        if (valid && f == j) atomicAdd(&cnt[p & 1023u], 1);
    }
    if (lane == 0 && myprev > 0) atomicAdd(&redbase, myprev);
    __syncthreads();
    int csr_base = ebeg + redbase;
    int c = cnt[tid];
    tmp[tid] = c; __syncthreads();
    for (int o = 1; o < 1024; o <<= 1) {
        int a = (tid >= o) ? tmp[tid - o] : 0;
        __syncthreads();
        tmp[tid] += a;
        __syncthreads();
    }
    int excl = tmp[tid] - c;
    int tot = tmp[1023];
    int i = node0 + tid;
    if (i < N) {
        rowptr[i] = csr_base + excl;
        float di = rsqrtf((float)c + 1.0f);
        dinv[i] = di;
        float2 xv = ((const float2*)x)[i];
        __half2 hz = __floats2half2_rn(xv.x * di, xv.y * di);
        z1h[i] = *(unsigned*)&hz;
    }
    cur[tid] = excl;
    __syncthreads();
    if (tot <= EB_CAP) {
        k0 = 0;
        for (; k0 + 8192 <= n; k0 += 8192) {
            unsigned p[8];
            #pragma unroll
            for (int u = 0; u < 8; ++u) p[u] = pk1[ebeg + k0 + tid + u * 1024];
            #pragma unroll
            for (int u = 0; u < 8; ++u) {
                if (((p[u] >> FINE_BITS) & 3u) == (unsigned)j) {
                    int pos = atomicAdd(&cur[p[u] & 1023u], 1);
                    eb[pos] = p[u] >> SBB;
                }
            }
        }
        for (int k = k0 + tid; k < n; k += 1024) {
            unsigned p = pk1[ebeg + k];
            if (((p >> FINE_BITS) & 3u) == (unsigned)j) {
                int pos = atomicAdd(&cur[p & 1023u], 1);
                eb[pos] = p >> SBB;
            }
        }
        __syncthreads();
        for (int k = tid; k < tot; k += 1024) csr[csr_base + k] = eb[k];
    } else {
        for (int k = tid; k < n; k += 1024) {
            unsigned p = pk1[ebeg + k];
            if (((p >> FINE_BITS) & 3u) == (unsigned)j) {
                int pos = atomicAdd(&cur[p & 1023u], 1);
                csr[csr_base + pos] = p >> SBB;
            }
        }
    }
}

// ---------------- GCN layers ----------------

__global__ void gcn1(const int* __restrict__ rowptr, const unsigned* __restrict__ csr,
                     const unsigned* __restrict__ z1h, const float* __restrict__ W1,
                     const float* __restrict__ b1, const float* __restrict__ dinv,
                     uint2* __restrict__ z2h, int N) {
    int i = blockIdx.x * blockDim.x + threadIdx.x;
    if (i >= N) return;
    int r0 = rowptr[i], r1 = rowptr[i + 1];
    float a0, a1;
    {
        unsigned zr = z1h[i];
        float2 zi = __half22float2(*(__half2*)&zr);
        a0 = zi.x; a1 = zi.y;
    }
    int k = r0;
    for (; k + 16 <= r1; k += 16) {
        unsigned j[16];
        #pragma unroll
        for (int u = 0; u < 16; ++u) j[u] = __builtin_nontemporal_load(&csr[k + u]);
        unsigned raw[16];
        #pragma unroll
        for (int u = 0; u < 16; ++u) raw[u] = z1h[j[u]];
        #pragma unroll
        for (int u = 0; u < 16; ++u) {
            float2 v = __half22float2(*(__half2*)&raw[u]);
            a0 += v.x; a1 += v.y;
        }
    }
    for (; k < r1; ++k) {
        unsigned zr = z1h[csr[k]];
        float2 zv = __half22float2(*(__half2*)&zr);
        a0 += zv.x; a1 += zv.y;
    }
    float di = dinv[i];
    float g0 = di * a0, g1 = di * a1;
    float o0 = di * tanhf(fmaf(g0, W1[0], fmaf(g1, W1[4], b1[0])));
    float o1 = di * tanhf(fmaf(g0, W1[1], fmaf(g1, W1[5], b1[1])));
    float o2 = di * tanhf(fmaf(g0, W1[2], fmaf(g1, W1[6], b1[2])));
    float o3 = di * tanhf(fmaf(g0, W1[3], fmaf(g1, W1[7], b1[3])));
    __half2 ha = __floats2half2_rn(o0, o1);
    __half2 hb = __floats2half2_rn(o2, o3);
    uint2 packed;
    packed.x = *(unsigned*)&ha;
    packed.y = *(unsigned*)&hb;
    z2h[i] = packed;
}

// ---- gcn2 pass A: aggregate contributions with src < NH (low 2MB half) ----
__global__ void gcn2a(const int* __restrict__ rowptr, const unsigned* __restrict__ csr,
                      const uint2* __restrict__ z2h,
                      unsigned long long* __restrict__ part, int N, unsigned NH) {
    int i = blockIdx.x * blockDim.x + threadIdx.x;
    if (i >= N) return;
    int r0 = rowptr[i], r1 = rowptr[i + 1];
    float a0 = 0.f, a1 = 0.f, a2 = 0.f, a3 = 0.f;
    if ((unsigned)i < NH) {  // self term lives in our half
        uint2 raw = z2h[i];
        float2 f01 = __half22float2(*(__half2*)&raw.x);
        float2 f23 = __half22float2(*(__half2*)&raw.y);
        a0 = f01.x; a1 = f01.y; a2 = f23.x; a3 = f23.y;
    }
    int k = r0;
    for (; k + 8 <= r1; k += 8) {
        unsigned j[8];
        #pragma unroll
        for (int u = 0; u < 8; ++u) j[u] = __builtin_nontemporal_load(&csr[k + u]);
        uint2 raw[8];
        #pragma unroll
        for (int u = 0; u < 8; ++u) {
            unsigned jj = (j[u] < NH) ? j[u] : 0u;  // dummy -> shared hot line
            raw[u] = z2h[jj];
        }
        #pragma unroll
        for (int u = 0; u < 8; ++u) {
            if (j[u] >= NH) { raw[u].x = 0u; raw[u].y = 0u; }  // +0.0 exact
            float2 f01 = __half22float2(*(__half2*)&raw[u].x);
            float2 f23 = __half22float2(*(__half2*)&raw[u].y);
            a0 += f01.x; a1 += f01.y; a2 += f23.x; a3 += f23.y;
        }
    }
    for (; k < r1; ++k) {
        unsigned j = csr[k];
        if (j < NH) {
            uint2 raw = z2h[j];
            float2 f01 = __half22float2(*(__half2*)&raw.x);
            float2 f23 = __half22float2(*(__half2*)&raw.y);
            a0 += f01.x; a1 += f01.y; a2 += f23.x; a3 += f23.y;
        }
    }
    unsigned long long p0 = (unsigned long long)__float_as_uint(a0) |
                            ((unsigned long long)__float_as_uint(a1) << 32);
    unsigned long long p1 = (unsigned long long)__float_as_uint(a2) |
                            ((unsigned long long)__float_as_uint(a3) << 32);
    __builtin_nontemporal_store(p0, &part[2 * (size_t)i]);
    __builtin_nontemporal_store(p1, &part[2 * (size_t)i + 1]);
}

// ---- gcn2 pass B: src >= NH (high 2MB half) + partials + epilogue ----
__global__ void gcn2b(const int* __restrict__ rowptr, const unsigned* __restrict__ csr,
                      const uint2* __restrict__ z2h, const float* __restrict__ W2,
                      const float* __restrict__ b2, const float* __restrict__ W3,
                      const float* __restrict__ dinv,
                      const unsigned long long* __restrict__ part,
                      unsigned* __restrict__ z3h, int N, unsigned NH) {
    int i = blockIdx.x * blockDim.x + threadIdx.x;
    if (i >= N) return;
    int r0 = rowptr[i], r1 = rowptr[i + 1];
    float a0, a1, a2, a3;
    {
        unsigned long long p0 = __builtin_nontemporal_load(&part[2 * (size_t)i]);
        unsigned long long p1 = __builtin_nontemporal_load(&part[2 * (size_t)i + 1]);
        a0 = __uint_as_float((unsigned)p0);
        a1 = __uint_as_float((unsigned)(p0 >> 32));
        a2 = __uint_as_float((unsigned)p1);
        a3 = __uint_as_float((unsigned)(p1 >> 32));
    }
    if ((unsigned)i >= NH) {  // self term lives in our half
        uint2 raw = z2h[i];
        float2 f01 = __half22float2(*(__half2*)&raw.x);
        float2 f23 = __half22float2(*(__half2*)&raw.y);
        a0 += f01.x; a1 += f01.y; a2 += f23.x; a3 += f23.y;
    }
    int k = r0;
    for (; k + 8 <= r1; k += 8) {
        unsigned j[8];
        #pragma unroll
        for (int u = 0; u < 8; ++u) j[u] = __builtin_nontemporal_load(&csr[k + u]);
        uint2 raw[8];
        #pragma unroll
        for (int u = 0; u < 8; ++u) {
            unsigned jj = (j[u] >= NH) ? j[u] : NH;  // dummy -> shared hot line
            raw[u] = z2h[jj];
        }
        #pragma unroll
        for (int u = 0; u < 8; ++u) {
            if (j[u] < NH) { raw[u].x = 0u; raw[u].y = 0u; }  // +0.0 exact
            float2 f01 = __half22float2(*(__half2*)&raw[u].x);
            float2 f23 = __half22float2(*(__half2*)&raw[u].y);
            a0 += f01.x; a1 += f01.y; a2 += f23.x; a3 += f23.y;
        }
    }
    for (; k < r1; ++k) {
        unsigned j = csr[k];
        if (j >= NH) {
            uint2 raw = z2h[j];
            float2 f01 = __half22float2(*(__half2*)&raw.x);
            float2 f23 = __half22float2(*(__half2*)&raw.y);
            a0 += f01.x; a1 += f01.y; a2 += f23.x; a3 += f23.y;
        }
    }
    float di = dinv[i];
    float g0 = di * a0, g1 = di * a1, g2 = di * a2, g3 = di * a3;
    float h[4];
    #pragma unroll
    for (int c = 0; c < 4; ++c)
        h[c] = tanhf(b2[c] + g0 * W2[c] + g1 * W2[4 + c] + g2 * W2[8 + c] + g3 * W2[12 + c]);
    float v0 = h[0] * W3[0] + h[1] * W3[2] + h[2] * W3[4] + h[3] * W3[6];
    float v1 = h[0] * W3[1] + h[1] * W3[3] + h[2] * W3[5] + h[3] * W3[7];
    __half2 hz = __floats2half2_rn(v0 * di, v1 * di);
    z3h[i] = *(unsigned*)&hz;
}

__global__ void gcn3(const int* __restrict__ rowptr, const unsigned* __restrict__ csr,
                     const unsigned* __restrict__ z3h, const float* __restrict__ b3,
                     const float* __restrict__ dinv, float* __restrict__ out, int N) {
    int i = blockIdx.x * blockDim.x + threadIdx.x;
    if (i >= N) return;
    int r0 = rowptr[i], r1 = rowptr[i + 1];
    float a0, a1;
    {
        unsigned zr = z3h[i];
        float2 zi = __half22float2(*(__half2*)&zr);
        a0 = zi.x; a1 = zi.y;
    }
    int k = r0;
    for (; k + 16 <= r1; k += 16) {
        unsigned j[16];
        #pragma unroll
        for (int u = 0; u < 16; ++u) j[u] = __builtin_nontemporal_load(&csr[k + u]);
        unsigned raw[16];
        #pragma unroll
        for (int u = 0; u < 16; ++u) raw[u] = z3h[j[u]];
        #pragma unroll
        for (int u = 0; u < 16; ++u) {
            float2 v = __half22float2(*(__half2*)&raw[u]);
            a0 += v.x; a1 += v.y;
        }
    }
    for (; k < r1; ++k) {
        unsigned zr = z3h[csr[k]];
        float2 zv = __half22float2(*(__half2*)&zr);
        a0 += zv.x; a1 += zv.y;
    }
    float di = dinv[i];
    ((float2*)out)[i] = make_float2(fmaf(di, a0, b3[0]), fmaf(di, a1, b3[1]));
}

extern "C" void kernel_launch(void* const* d_in, const int* in_sizes, int n_in,
                              void* d_out, int out_size, void* d_ws, size_t ws_size,
                              hipStream_t stream) {
    const float* x  = (const float*)d_in[0];
    const int*   ei = (const int*)d_in[1];
    const float* W1 = (const float*)d_in[2];
    const float* b1 = (const float*)d_in[3];
    const float* W2 = (const float*)d_in[4];
    const float* b2 = (const float*)d_in[5];
    const float* W3 = (const float*)d_in[6];
    const float* b3 = (const float*)d_in[7];
    float* out = (float*)d_out;

    const int N = in_sizes[0] / 2;
    const int E = in_sizes[1] / 2;
    const int* src = ei;
    const int* dst = ei + E;

    const int SB  = (N + (1 << SBB) - 1) >> SBB;     // 123 superbuckets
    const int ntB = (E + T_TILE - 1) / T_TILE;       // 489 tiles of 32K edges
    const int mlen = SB * ntB;                       // ~60K
    const int NB = (mlen + 1023) / 1024;             // ~59
    const unsigned NH = (unsigned)(N / 2);           // src-space split point

    // ws layout (256B-aligned)
    auto align = [](size_t o) { return (o + 255) & ~(size_t)255; };
    char* wbase = (char*)d_ws;
    size_t off = 0;
    float*    dinv   = (float*)(wbase + off);    off = align(off + (size_t)N * 4);
    unsigned* z1h    = (unsigned*)(wbase + off); off = align(off + (size_t)N * 4);
    uint2*    z2h    = (uint2*)(wbase + off);    off = align(off + (size_t)N * 8);
    unsigned* z3h    = (unsigned*)(wbase + off); off = align(off + (size_t)N * 4);
    unsigned long long* part = (unsigned long long*)(wbase + off);
    off = align(off + (size_t)N * 16);
    int*      rowptr = (int*)(wbase + off);      off = align(off + (size_t)(N + 1) * 4);
    int*      bsum   = (int*)(wbase + off);      off = align(off + (size_t)1024 * 4);
    int*      bases1 = (int*)(wbase + off);      off = align(off + (size_t)(SB + 1) * 4);
    int*      cnt1   = (int*)(wbase + off);      off = align(off + (size_t)mlen * 4);
    unsigned* pk1    = (unsigned*)(wbase + off); off = align(off + (size_t)E * 4);
    unsigned* csr    = (unsigned*)(wbase + off); off = align(off + (size_t)E * 4);

    dim3 gN((N + TPB - 1) / TPB);
    count1<<<dim3(ntB), dim3(512), 0, stream>>>(dst, cnt1, ntB, E, SB);
    scan_k1<<<dim3(NB), dim3(TPB), 0, stream>>>(cnt1, bsum, mlen);
    scan_k2<<<dim3(1), dim3(1024), 0, stream>>>(bsum, NB);
    scan_k3<<<dim3(NB), dim3(TPB), 0, stream>>>(cnt1, bsum, mlen);
    bases_fix<<<dim3(1), dim3(256), 0, stream>>>(cnt1, ntB, SB, bases1, rowptr, N, E);
    scatter1<<<dim3(ntB), dim3(512), 0, stream>>>(dst, src, cnt1, pk1, ntB, E, SB);
    buildfine<<<dim3(SB * 4), dim3(1024), 0, stream>>>(bases1, pk1, x, rowptr, dinv,
                                                       z1h, csr, N);
    gcn1<<<gN, dim3(TPB), 0, stream>>>(rowptr, csr, z1h, W1, b1, dinv, z2h, N);
    gcn2a<<<gN, dim3(TPB), 0, stream>>>(rowptr, csr, z2h, part, N, NH);
    gcn2b<<<gN, dim3(TPB), 0, stream>>>(rowptr, csr, z2h, W2, b2, W3, dinv, part,
                                        z3h, N, NH);
    gcn3<<<gN, dim3(TPB), 0, stream>>>(rowptr, csr, z3h, b3, dinv, out, N);
}

// Round 3
// 781.217 us; speedup vs baseline: 1.1010x; 1.1010x over previous
//
#include <hip/hip_runtime.h>
#include <hip/hip_fp16.h>

// GCN 3-layer. Two-pass build: scatter1 -> 123 superbuckets of 4096 nodes,
// buildfine -> block per 1024-node fine bucket, in-LDS counting sort ->
// csr + rowptr/dinv/z1 fused. Layers: thread-per-node unrolled gathers.
// R13: z2 4xfp16 (8B/node, 4MB table). R14: z1/z3 half2 (4B/node, 2MB tables).
// R15 (REVERTED): src-partitioned gcn2 — 2MB residency win < extra 64MB csr
// stream cost (total +44us). gcn2 stays single-pass.
// R16 change: scatter1 was 136us at 13% HBM, FETCH+WRITE=143MB -> scattered
// 4B-write bound (~47 distinct lines per wave-store). New scatter1: tile=16K,
// in-LDS counting sort (64KB staged tile, 2 blocks/CU): histogram tile
// (pass-B dst re-read is L2-hit), 128-scan, atomic-cursor place into LDS,
// then per-bucket contiguous coalesced flush to global base. pk1 layout
// identical (per-(bucket,tile) cell order irrelevant). ~12x fewer write-line
// transactions.
// Math per layer (input u): z = u*dinv; s_i = sum_{e:dst=i} z[src_e];
//   out_i = (dinv_i*(s_i + z_i)) @ W + b   (self-loop folds into s+z).
// pk1 = (dst&4095) | (src<<12)  (31 bits, N < 2^19).

#define TPB 256
#define T_TILE 16384
#define SBB 12           // superbucket = 4096 nodes
#define NSB_MAX 128
#define FINE_BITS 10     // fine bucket = 1024 nodes, 4 per superbucket
#define EB_CAP 34048     // mean fine bucket 32.7K edges, +7 sigma

// ---------------- pass 0: per-tile superbucket histogram ----------------

__global__ void __launch_bounds__(512)
count1(const int* __restrict__ dst, int* __restrict__ cnt1, int ntB, int E, int SB) {
    __shared__ int hist[NSB_MAX];
    int blk = blockIdx.x, tid = threadIdx.x;
    if (tid < SB) hist[tid] = 0;
    __syncthreads();
    int base = blk * T_TILE;
    #pragma unroll 8
    for (int it = 0; it < T_TILE / 512; ++it) {
        int e = base + it * 512 + tid;
        if (e < E) atomicAdd(&hist[((unsigned)dst[e]) >> SBB], 1);
    }
    __syncthreads();
    if (tid < SB) cnt1[(size_t)tid * ntB + blk] = hist[tid];
}

// ---- 3-kernel exclusive scan over data[len] (in-place), 1024 elems/block ----
__global__ void scan_k1(const int* __restrict__ data, int* __restrict__ bsum, int len) {
    __shared__ int lds[TPB];
    int b = blockIdx.x, t = threadIdx.x;
    int base = b * 1024 + t * 4;
    int s = 0;
    #pragma unroll
    for (int j = 0; j < 4; ++j) { int i = base + j; if (i < len) s += data[i]; }
    lds[t] = s; __syncthreads();
    for (int off = 128; off > 0; off >>= 1) {
        if (t < off) lds[t] += lds[t + off];
        __syncthreads();
    }
    if (t == 0) bsum[b] = lds[0];
}

__global__ void scan_k2(int* __restrict__ bsum, int NB) {
    __shared__ int lds[1024];
    int t = threadIdx.x;
    int v = (t < NB) ? bsum[t] : 0;
    lds[t] = v; __syncthreads();
    for (int off = 1; off < 1024; off <<= 1) {
        int add = (t >= off) ? lds[t - off] : 0;
        __syncthreads();
        lds[t] += add;
        __syncthreads();
    }
    if (t < NB) bsum[t] = lds[t] - v;  // exclusive
}

__global__ void scan_k3(int* __restrict__ data, const int* __restrict__ bsum, int len) {
    __shared__ int lds[TPB];
    int b = blockIdx.x, t = threadIdx.x;
    int base = b * 1024 + t * 4;
    int v[4]; int s = 0;
    #pragma unroll
    for (int j = 0; j < 4; ++j) { int i = base + j; v[j] = (i < len) ? data[i] : 0; s += v[j]; }
    int orig = s;
    lds[t] = s; __syncthreads();
    for (int off = 1; off < 256; off <<= 1) {
        int add = (t >= off) ? lds[t - off] : 0;
        __syncthreads();
        lds[t] += add;
        __syncthreads();
    }
    int run = bsum[b] + lds[t] - orig;
    #pragma unroll
    for (int j = 0; j < 4; ++j) {
        int i = base + j;
        if (i < len) { data[i] = run; run += v[j]; }
    }
}

__global__ void bases_fix(const int* __restrict__ cnt1, int ntB, int SB,
                          int* __restrict__ bases1, int* __restrict__ rowptr,
                          int N, int E) {
    int t = threadIdx.x;
    if (t < SB) bases1[t] = cnt1[(size_t)t * ntB];
    if (t == 0) { bases1[SB] = E; rowptr[N] = E; }
}

// ---- pass 1: in-LDS counting-sort scatter (coalesced write-back) ----
__global__ void __launch_bounds__(512)
scatter1(const int* __restrict__ dst, const int* __restrict__ src,
         const int* __restrict__ cnt1, unsigned* __restrict__ pk1,
         int ntB, int E, int SB) {
    __shared__ unsigned lpk[T_TILE];   // 64KB staged packed values
    __shared__ int lhist[NSB_MAX];
    __shared__ int lexcl[NSB_MAX];
    __shared__ int lcur[NSB_MAX];
    __shared__ int basec[NSB_MAX];
    int blk = blockIdx.x, tid = threadIdx.x;
    if (tid < NSB_MAX) lhist[tid] = 0;
    if (tid < SB) basec[tid] = cnt1[(size_t)tid * ntB + blk];
    __syncthreads();
    int base = blk * T_TILE;
    // pass A: tile histogram (dst slice = 64KB -> stays L2-hot for pass B)
    #pragma unroll 8
    for (int it = 0; it < T_TILE / 512; ++it) {
        int e = base + it * 512 + tid;
        if (e < E) atomicAdd(&lhist[((unsigned)dst[e]) >> SBB], 1);
    }
    __syncthreads();
    // exclusive scan over the 128 bucket counts
    int hv = (tid < NSB_MAX) ? lhist[tid] : 0;
    if (tid < NSB_MAX) lexcl[tid] = hv;
    __syncthreads();
    for (int off = 1; off < NSB_MAX; off <<= 1) {
        int a = (tid < NSB_MAX && tid >= off) ? lexcl[tid - off] : 0;
        __syncthreads();
        if (tid < NSB_MAX) lexcl[tid] += a;
        __syncthreads();
    }
    if (tid < NSB_MAX) { lexcl[tid] -= hv; lcur[tid] = lexcl[tid]; }
    __syncthreads();
    // pass B: place packed values into LDS at sorted positions
    #pragma unroll 8
    for (int it = 0; it < T_TILE / 512; ++it) {
        int e = base + it * 512 + tid;
        if (e < E) {
            unsigned d = (unsigned)dst[e];
            unsigned s = (unsigned)src[e];
            int pos = atomicAdd(&lcur[d >> SBB], 1);
            lpk[pos] = (d & 4095u) | (s << SBB);
        }
    }
    __syncthreads();
    // flush: per-bucket contiguous copy (coalesced global writes)
    for (int b = 0; b < SB; ++b) {
        int lo = lexcl[b], cntb = lhist[b], gb = basec[b];
        for (int t2 = tid; t2 < cntb; t2 += 512)
            pk1[gb + t2] = lpk[lo + t2];
    }
}

// ---- pass 2: fused fine+node sort -> csr + rowptr + dinv + z1 (half2) ----
__global__ void __launch_bounds__(1024)
buildfine(const int* __restrict__ bases1, const unsigned* __restrict__ pk1,
          const float* __restrict__ x, int* __restrict__ rowptr,
          float* __restrict__ dinv, unsigned* __restrict__ z1h,
          unsigned* __restrict__ csr, int N) {
    __shared__ int cnt[1024];
    __shared__ int tmp[1024];
    __shared__ int cur[1024];
    __shared__ unsigned eb[EB_CAP];
    __shared__ int redbase;
    int bid = blockIdx.x, tid = threadIdx.x;
    int sb = bid >> 2, j = bid & 3;
    int node0 = (sb << SBB) + (j << FINE_BITS);
    int ebeg = bases1[sb], eend = bases1[sb + 1];
    int n = eend - ebeg;
    cnt[tid] = 0;
    if (tid == 0) redbase = 0;
    __syncthreads();
    int lane = tid & 63;
    int myprev = 0;  // wave count of region edges with fine-id < j
    int k0 = 0;
    for (; k0 + 8192 <= n; k0 += 8192) {
        unsigned p[8];
        #pragma unroll
        for (int u = 0; u < 8; ++u) p[u] = pk1[ebeg + k0 + tid + u * 1024];
        #pragma unroll
        for (int u = 0; u < 8; ++u) {
            int f = (int)((p[u] >> FINE_BITS) & 3u);
            myprev += (int)__popcll(__ballot(f < j));
            if (f == j) atomicAdd(&cnt[p[u] & 1023u], 1);
        }
    }
    for (int kk = k0; kk < n; kk += 1024) {
        int k = kk + tid;
        bool valid = (k < n);
        unsigned p = valid ? pk1[ebeg + k] : 0u;
        int f = valid ? (int)((p >> FINE_BITS) & 3u) : 4;
        myprev += (int)__popcll(__ballot(valid && f < j));
        if (valid && f == j) atomicAdd(&cnt[p & 1023u], 1);
    }
    if (lane == 0 && myprev > 0) atomicAdd(&redbase, myprev);
    __syncthreads();
    int csr_base = ebeg + redbase;
    int c = cnt[tid];
    tmp[tid] = c; __syncthreads();
    for (int o = 1; o < 1024; o <<= 1) {
        int a = (tid >= o) ? tmp[tid - o] : 0;
        __syncthreads();
        tmp[tid] += a;
        __syncthreads();
    }
    int excl = tmp[tid] - c;
    int tot = tmp[1023];
    int i = node0 + tid;
    if (i < N) {
        rowptr[i] = csr_base + excl;
        float di = rsqrtf((float)c + 1.0f);
        dinv[i] = di;
        float2 xv = ((const float2*)x)[i];
        __half2 hz = __floats2half2_rn(xv.x * di, xv.y * di);
        z1h[i] = *(unsigned*)&hz;
    }
    cur[tid] = excl;
    __syncthreads();
    if (tot <= EB_CAP) {
        k0 = 0;
        for (; k0 + 8192 <= n; k0 += 8192) {
            unsigned p[8];
            #pragma unroll
            for (int u = 0; u < 8; ++u) p[u] = pk1[ebeg + k0 + tid + u * 1024];
            #pragma unroll
            for (int u = 0; u < 8; ++u) {
                if (((p[u] >> FINE_BITS) & 3u) == (unsigned)j) {
                    int pos = atomicAdd(&cur[p[u] & 1023u], 1);
                    eb[pos] = p[u] >> SBB;
                }
            }
        }
        for (int k = k0 + tid; k < n; k += 1024) {
            unsigned p = pk1[ebeg + k];
            if (((p >> FINE_BITS) & 3u) == (unsigned)j) {
                int pos = atomicAdd(&cur[p & 1023u], 1);
                eb[pos] = p >> SBB;
            }
        }
        __syncthreads();
        for (int k = tid; k < tot; k += 1024) csr[csr_base + k] = eb[k];
    } else {
        for (int k = tid; k < n; k += 1024) {
            unsigned p = pk1[ebeg + k];
            if (((p >> FINE_BITS) & 3u) == (unsigned)j) {
                int pos = atomicAdd(&cur[p & 1023u], 1);
                csr[csr_base + pos] = p >> SBB;
            }
        }
    }
}

// ---------------- GCN layers ----------------

__global__ void gcn1(const int* __restrict__ rowptr, const unsigned* __restrict__ csr,
                     const unsigned* __restrict__ z1h, const float* __restrict__ W1,
                     const float* __restrict__ b1, const float* __restrict__ dinv,
                     uint2* __restrict__ z2h, int N) {
    int i = blockIdx.x * blockDim.x + threadIdx.x;
    if (i >= N) return;
    int r0 = rowptr[i], r1 = rowptr[i + 1];
    float a0, a1;
    {
        unsigned zr = z1h[i];
        float2 zi = __half22float2(*(__half2*)&zr);
        a0 = zi.x; a1 = zi.y;
    }
    int k = r0;
    for (; k + 16 <= r1; k += 16) {
        unsigned j[16];
        #pragma unroll
        for (int u = 0; u < 16; ++u) j[u] = __builtin_nontemporal_load(&csr[k + u]);
        unsigned raw[16];
        #pragma unroll
        for (int u = 0; u < 16; ++u) raw[u] = z1h[j[u]];
        #pragma unroll
        for (int u = 0; u < 16; ++u) {
            float2 v = __half22float2(*(__half2*)&raw[u]);
            a0 += v.x; a1 += v.y;
        }
    }
    for (; k < r1; ++k) {
        unsigned zr = z1h[csr[k]];
        float2 zv = __half22float2(*(__half2*)&zr);
        a0 += zv.x; a1 += zv.y;
    }
    float di = dinv[i];
    float g0 = di * a0, g1 = di * a1;
    float o0 = di * tanhf(fmaf(g0, W1[0], fmaf(g1, W1[4], b1[0])));
    float o1 = di * tanhf(fmaf(g0, W1[1], fmaf(g1, W1[5], b1[1])));
    float o2 = di * tanhf(fmaf(g0, W1[2], fmaf(g1, W1[6], b1[2])));
    float o3 = di * tanhf(fmaf(g0, W1[3], fmaf(g1, W1[7], b1[3])));
    __half2 ha = __floats2half2_rn(o0, o1);
    __half2 hb = __floats2half2_rn(o2, o3);
    uint2 packed;
    packed.x = *(unsigned*)&ha;
    packed.y = *(unsigned*)&hb;
    z2h[i] = packed;
}

__global__ void gcn2(const int* __restrict__ rowptr, const unsigned* __restrict__ csr,
                     const uint2* __restrict__ z2h, const float* __restrict__ W2,
                     const float* __restrict__ b2, const float* __restrict__ W3,
                     const float* __restrict__ dinv, unsigned* __restrict__ z3h, int N) {
    int i = blockIdx.x * blockDim.x + threadIdx.x;
    if (i >= N) return;
    int r0 = rowptr[i], r1 = rowptr[i + 1];
    float a0, a1, a2, a3;
    {
        uint2 raw = z2h[i];
        float2 f01 = __half22float2(*(__half2*)&raw.x);
        float2 f23 = __half22float2(*(__half2*)&raw.y);
        a0 = f01.x; a1 = f01.y; a2 = f23.x; a3 = f23.y;
    }
    int k = r0;
    for (; k + 8 <= r1; k += 8) {
        unsigned j[8];
        #pragma unroll
        for (int u = 0; u < 8; ++u) j[u] = __builtin_nontemporal_load(&csr[k + u]);
        uint2 raw[8];
        #pragma unroll
        for (int u = 0; u < 8; ++u) raw[u] = z2h[j[u]];
        #pragma unroll
        for (int u = 0; u < 8; ++u) {
            float2 f01 = __half22float2(*(__half2*)&raw[u].x);
            float2 f23 = __half22float2(*(__half2*)&raw[u].y);
            a0 += f01.x; a1 += f01.y; a2 += f23.x; a3 += f23.y;
        }
    }
    for (; k < r1; ++k) {
        uint2 raw = z2h[csr[k]];
        float2 f01 = __half22float2(*(__half2*)&raw.x);
        float2 f23 = __half22float2(*(__half2*)&raw.y);
        a0 += f01.x; a1 += f01.y; a2 += f23.x; a3 += f23.y;
    }
    float di = dinv[i];
    float g0 = di * a0, g1 = di * a1, g2 = di * a2, g3 = di * a3;
    float h[4];
    #pragma unroll
    for (int c = 0; c < 4; ++c)
        h[c] = tanhf(b2[c] + g0 * W2[c] + g1 * W2[4 + c] + g2 * W2[8 + c] + g3 * W2[12 + c]);
    float v0 = h[0] * W3[0] + h[1] * W3[2] + h[2] * W3[4] + h[3] * W3[6];
    float v1 = h[0] * W3[1] + h[1] * W3[3] + h[2] * W3[5] + h[3] * W3[7];
    __half2 hz = __floats2half2_rn(v0 * di, v1 * di);
    z3h[i] = *(unsigned*)&hz;
}

__global__ void gcn3(const int* __restrict__ rowptr, const unsigned* __restrict__ csr,
                     const unsigned* __restrict__ z3h, const float* __restrict__ b3,
                     const float* __restrict__ dinv, float* __restrict__ out, int N) {
    int i = blockIdx.x * blockDim.x + threadIdx.x;
    if (i >= N) return;
    int r0 = rowptr[i], r1 = rowptr[i + 1];
    float a0, a1;
    {
        unsigned zr = z3h[i];
        float2 zi = __half22float2(*(__half2*)&zr);
        a0 = zi.x; a1 = zi.y;
    }
    int k = r0;
    for (; k + 16 <= r1; k += 16) {
        unsigned j[16];
        #pragma unroll
        for (int u = 0; u < 16; ++u) j[u] = __builtin_nontemporal_load(&csr[k + u]);
        unsigned raw[16];
        #pragma unroll
        for (int u = 0; u < 16; ++u) raw[u] = z3h[j[u]];
        #pragma unroll
        for (int u = 0; u < 16; ++u) {
            float2 v = __half22float2(*(__half2*)&raw[u]);
            a0 += v.x; a1 += v.y;
        }
    }
    for (; k < r1; ++k) {
        unsigned zr = z3h[csr[k]];
        float2 zv = __half22float2(*(__half2*)&zr);
        a0 += zv.x; a1 += zv.y;
    }
    float di = dinv[i];
    ((float2*)out)[i] = make_float2(fmaf(di, a0, b3[0]), fmaf(di, a1, b3[1]));
}

extern "C" void kernel_launch(void* const* d_in, const int* in_sizes, int n_in,
                              void* d_out, int out_size, void* d_ws, size_t ws_size,
                              hipStream_t stream) {
    const float* x  = (const float*)d_in[0];
    const int*   ei = (const int*)d_in[1];
    const float* W1 = (const float*)d_in[2];
    const float* b1 = (const float*)d_in[3];
    const float* W2 = (const float*)d_in[4];
    const float* b2 = (const float*)d_in[5];
    const float* W3 = (const float*)d_in[6];
    const float* b3 = (const float*)d_in[7];
    float* out = (float*)d_out;

    const int N = in_sizes[0] / 2;
    const int E = in_sizes[1] / 2;
    const int* src = ei;
    const int* dst = ei + E;

    const int SB  = (N + (1 << SBB) - 1) >> SBB;     // 123 superbuckets
    const int ntB = (E + T_TILE - 1) / T_TILE;       // 977 tiles of 16K edges
    const int mlen = SB * ntB;                       // ~120K
    const int NB = (mlen + 1023) / 1024;             // ~118

    // ws layout (256B-aligned)
    auto align = [](size_t o) { return (o + 255) & ~(size_t)255; };
    char* wbase = (char*)d_ws;
    size_t off = 0;
    float*    dinv   = (float*)(wbase + off);    off = align(off + (size_t)N * 4);
    unsigned* z1h    = (unsigned*)(wbase + off); off = align(off + (size_t)N * 4);
    uint2*    z2h    = (uint2*)(wbase + off);    off = align(off + (size_t)N * 8);
    unsigned* z3h    = (unsigned*)(wbase + off); off = align(off + (size_t)N * 4);
    int*      rowptr = (int*)(wbase + off);      off = align(off + (size_t)(N + 1) * 4);
    int*      bsum   = (int*)(wbase + off);      off = align(off + (size_t)1024 * 4);
    int*      bases1 = (int*)(wbase + off);      off = align(off + (size_t)(SB + 1) * 4);
    int*      cnt1   = (int*)(wbase + off);      off = align(off + (size_t)mlen * 4);
    unsigned* pk1    = (unsigned*)(wbase + off); off = align(off + (size_t)E * 4);
    unsigned* csr    = (unsigned*)(wbase + off); off = align(off + (size_t)E * 4);

    dim3 gN((N + TPB - 1) / TPB);
    count1<<<dim3(ntB), dim3(512), 0, stream>>>(dst, cnt1, ntB, E, SB);
    scan_k1<<<dim3(NB), dim3(TPB), 0, stream>>>(cnt1, bsum, mlen);
    scan_k2<<<dim3(1), dim3(1024), 0, stream>>>(bsum, NB);
    scan_k3<<<dim3(NB), dim3(TPB), 0, stream>>>(cnt1, bsum, mlen);
    bases_fix<<<dim3(1), dim3(256), 0, stream>>>(cnt1, ntB, SB, bases1, rowptr, N, E);
    scatter1<<<dim3(ntB), dim3(512), 0, stream>>>(dst, src, cnt1, pk1, ntB, E, SB);
    buildfine<<<dim3(SB * 4), dim3(1024), 0, stream>>>(bases1, pk1, x, rowptr, dinv,
                                                       z1h, csr, N);
    gcn1<<<gN, dim3(TPB), 0, stream>>>(rowptr, csr, z1h, W1, b1, dinv, z2h, N);
    gcn2<<<gN, dim3(TPB), 0, stream>>>(rowptr, csr, z2h, W2, b2, W3, dinv, z3h, N);
    gcn3<<<gN, dim3(TPB), 0, stream>>>(rowptr, csr, z3h, b3, dinv, out, N);
}